// Round 13
// baseline (468.338 us; speedup 1.0000x reference)
//
#include <hip/hip_runtime.h>
#include <hip/hip_bf16.h>

#define D 96
typedef long long i64;

__device__ __forceinline__ float bf2f(unsigned short u) {
  union { unsigned u; float f; } x; x.u = ((unsigned)u) << 16; return x.f;
}
__device__ __forceinline__ void unpack8(uint4 p, float* a) {
  a[0] = bf2f((unsigned short)(p.x & 0xffff)); a[1] = bf2f((unsigned short)(p.x >> 16));
  a[2] = bf2f((unsigned short)(p.y & 0xffff)); a[3] = bf2f((unsigned short)(p.y >> 16));
  a[4] = bf2f((unsigned short)(p.z & 0xffff)); a[5] = bf2f((unsigned short)(p.z >> 16));
  a[6] = bf2f((unsigned short)(p.w & 0xffff)); a[7] = bf2f((unsigned short)(p.w >> 16));
}

// ---- fused: zero cnt + index-width detection (block 0) ----
__global__ __launch_bounds__(256) void k_zero_detect(int* cur, int N,
                                                     const unsigned* __restrict__ w,
                                                     int* flag, int E) {
  int i = blockIdx.x * 256 + threadIdx.x;
  if (i < N) cur[i] = 0;
  if (blockIdx.x == 0 && threadIdx.x < 64) {
    int lane = threadIdx.x;
    int lim = (E < 2048) ? E : 2048;
    unsigned acc = 0;
    for (int j = lane; j < lim; j += 64) acc |= w[2 * j + 1];
#pragma unroll
    for (int off = 32; off > 0; off >>= 1) acc |= __shfl_down(acc, off, 64);
    if (lane == 0) *flag = (acc == 0) ? 1 : 0;  // 1 => int64 storage
  }
}

// ---- histogram of dst, range-partitioned (no cross-XCD line sharing) ----
__global__ __launch_bounds__(256) void k_hist(const int* __restrict__ e32,
                                              const i64* __restrict__ e64,
                                              const int* __restrict__ flagp,
                                              int* cnt, int E, int N) {
  int range = blockIdx.x & 7;
  int sub = blockIdx.x >> 3;
  int B = gridDim.x >> 3;
  int chunk = (E + B - 1) / B;
  int lo = sub * chunk;
  int hi = min(E, lo + chunk);
  int f = *flagp;
  int rlo = (int)(((i64)N * range) >> 3);
  int rhi = (int)(((i64)N * (range + 1)) >> 3);
  for (int i = lo + threadIdx.x; i < hi; i += 256) {
    int d = f ? (int)e64[(size_t)E + i] : e32[(size_t)E + i];
    if (d < rlo || d >= rhi) continue;
    atomicAdd(&cnt[d], 1);
  }
}

// ---- scan phase 1: per-block exclusive scan; fused dinv = rsqrt(cnt+1) ----
__global__ __launch_bounds__(1024) void k_scan1(const int* __restrict__ cnt,
                                                int* __restrict__ off,
                                                float* __restrict__ dinv,
                                                int* __restrict__ bsum, int N) {
  __shared__ int tmp[1024];
  int tid = threadIdx.x;
  int i = blockIdx.x * 1024 + tid;
  int v = (i < N) ? cnt[i] : 0;
  if (i < N) dinv[i] = rsqrtf((float)v + 1.0f);
  tmp[tid] = v;
  __syncthreads();
  for (int s = 1; s < 1024; s <<= 1) {
    int add = (tid >= s) ? tmp[tid - s] : 0;
    __syncthreads();
    tmp[tid] += add;
    __syncthreads();
  }
  if (i < N) off[i] = tmp[tid] - v;
  if (tid == 1023) bsum[blockIdx.x] = tmp[1023];
}

// ---- scan phase 2 ----
__global__ __launch_bounds__(1024) void k_scan2(int* __restrict__ bsum, int* __restrict__ off,
                                                int NB, int N) {
  __shared__ int tmp[1024];
  int tid = threadIdx.x;
  int v = (tid < NB) ? bsum[tid] : 0;
  tmp[tid] = v;
  __syncthreads();
  for (int s = 1; s < 1024; s <<= 1) {
    int add = (tid >= s) ? tmp[tid - s] : 0;
    __syncthreads();
    tmp[tid] += add;
    __syncthreads();
  }
  if (tid < NB) bsum[tid] = tmp[tid] - v;
  if (tid == NB - 1) off[N] = tmp[tid];
}

// ---- scan phase 3 ----
__global__ __launch_bounds__(1024) void k_scan3(int* __restrict__ off, int* __restrict__ cur,
                                                const int* __restrict__ bsum, int N) {
  int i = blockIdx.x * 1024 + threadIdx.x;
  if (i >= N) return;
  int o = off[i] + bsum[blockIdx.x];
  off[i] = o;
  cur[i] = o;
}

// ---- fill CSR, range-partitioned ----
__global__ __launch_bounds__(256) void k_fill(const int* __restrict__ e32,
                                              const i64* __restrict__ e64,
                                              const int* __restrict__ flagp,
                                              int* cur, int* __restrict__ csr, int E, int N) {
  int range = blockIdx.x & 7;
  int sub = blockIdx.x >> 3;
  int B = gridDim.x >> 3;
  int chunk = (E + B - 1) / B;
  int lo = sub * chunk;
  int hi = min(E, lo + chunk);
  int f = *flagp;
  int rlo = (int)(((i64)N * range) >> 3);
  int rhi = (int)(((i64)N * (range + 1)) >> 3);
  for (int i = lo + threadIdx.x; i < hi; i += 256) {
    int d = f ? (int)e64[(size_t)E + i] : e32[(size_t)E + i];
    if (d < rlo || d >= rhi) continue;
    int s = f ? (int)e64[i] : e32[i];
    if ((unsigned)s >= (unsigned)N) continue;
    int pos = atomicAdd(&cur[d], 1);
    csr[pos] = s;
  }
}

// ---- GEMM: t[i,:] = bf16( dinv[i] * (A[i,:] @ W) ) ----
// R10 64x96 tile, single LDS buffer, 2 barriers/chunk + REGISTER PREFETCH:
// chunk c+1's global loads issue before compute(c) (latency overlapped).
// Outer loop NOT unrolled (R11 lesson: full unroll + live float4s -> VGPR 256 spill).
template <int KTOT, int MODE>
__global__ __launch_bounds__(256) void gemm_kernel(
    const float* __restrict__ xin, const float* __restrict__ xg,
    const float* __restrict__ hprev, const float* __restrict__ gmul,
    const float* __restrict__ W, const float* __restrict__ dinv,
    __hip_bfloat16* __restrict__ t, int N) {
  __shared__ float As[32][68];   // [k][row]; 272B stride (16B aligned)
  __shared__ float Ws[32][96];
  const int tid = threadIdx.x;
  const int tx = tid & 15;       // col group (6 cols)
  const int ty = tid >> 4;       // row group (4 rows)
  const int row0 = blockIdx.x * 64;
  const int srow = tid >> 3;     // staging row 0..31 (+32 for second)
  const int skf = tid & 7;       // staging k-quad
  constexpr int C = KTOT / 32;
  float acc[4][6] = {};
  float4 va[2], vw[3];

  auto loadChunk = [&](int kc) {
#pragma unroll
    for (int i = 0; i < 2; i++) {
      int grow = row0 + srow + i * 32;
      int gk = kc + 4 * skf;
      float4 v = make_float4(0.f, 0.f, 0.f, 0.f);
      if (grow < N) {
        if (MODE == 0) {
          v = *(const float4*)&xin[(size_t)grow * D + gk];
        } else if (gk < 96) {
          v = *(const float4*)&xg[(size_t)grow * D + gk];
        } else {
          v = *(const float4*)&hprev[(size_t)grow * D + (gk - 96)];
          if (MODE == 2) {
            float4 gm = *(const float4*)&gmul[(size_t)grow * D + (gk - 96)];
            v.x *= gm.x; v.y *= gm.y; v.z *= gm.z; v.w *= gm.w;
          }
        }
      }
      va[i] = v;
    }
#pragma unroll
    for (int i = 0; i < 3; i++) {
      int e = tid + i * 256;
      int k = e / 24, c4 = e - k * 24;
      vw[i] = *(const float4*)&W[(size_t)(kc + k) * D + 4 * c4];
    }
  };
  auto storeChunk = [&]() {
    int k0 = 4 * skf;
#pragma unroll
    for (int i = 0; i < 2; i++) {
      int row = srow + i * 32;
      As[k0 + 0][row] = va[i].x;
      As[k0 + 1][row] = va[i].y;
      As[k0 + 2][row] = va[i].z;
      As[k0 + 3][row] = va[i].w;
    }
#pragma unroll
    for (int i = 0; i < 3; i++) {
      int e = tid + i * 256;
      int k = e / 24, c4 = e - k * 24;
      *(float4*)&Ws[k][4 * c4] = vw[i];
    }
  };

  loadChunk(0);
  storeChunk();
  __syncthreads();
#pragma unroll 1
  for (int c = 0; c < C; c++) {
    if (c + 1 < C) loadChunk((c + 1) * 32);  // in-flight during compute
#pragma unroll
    for (int k = 0; k < 32; k++) {
      float4 a4 = *(const float4*)&As[k][ty * 4];
      float2 b01 = *(const float2*)&Ws[k][tx * 6];
      float2 b23 = *(const float2*)&Ws[k][tx * 6 + 2];
      float2 b45 = *(const float2*)&Ws[k][tx * 6 + 4];
      float a[4] = {a4.x, a4.y, a4.z, a4.w};
      float b[6] = {b01.x, b01.y, b23.x, b23.y, b45.x, b45.y};
#pragma unroll
      for (int r = 0; r < 4; r++)
#pragma unroll
        for (int cc = 0; cc < 6; cc++) acc[r][cc] += a[r] * b[cc];
    }
    if (c + 1 < C) {
      __syncthreads();   // all reads of LDS done
      storeChunk();
      __syncthreads();   // new chunk published
    }
  }
#pragma unroll
  for (int r = 0; r < 4; r++) {
    int grow = row0 + ty * 4 + r;
    if (grow >= N) continue;
    float dv = dinv[grow];
#pragma unroll
    for (int c = 0; c < 6; c++) {
      int gc = tx * 6 + c;
      t[(size_t)grow * D + gc] = __float2bfloat16(acc[r][c] * dv);
    }
  }
}

// ---- fused gather-reduce + finalize: bf16 t, 8-elem chunks (12 threads/node) ----
template <int MODE>
__global__ __launch_bounds__(256) void gather_fin(
    const __hip_bfloat16* __restrict__ t, const float* __restrict__ dinv,
    const int* __restrict__ off, const int* __restrict__ csr,
    const float* __restrict__ bias,
    const float* __restrict__ g, const float* __restrict__ hprev,
    float* __restrict__ outf, int N) {
  int idx = blockIdx.x * 256 + threadIdx.x;
  int total = N * 12;
  if (idx >= total) return;
  int v = idx / 12;
  int c8 = idx - v * 12;
  const uint4* t8 = (const uint4*)t;
  float acc[8];
  unpack8(t8[(size_t)v * 12 + c8], acc);
  int b0 = off[v], b1 = off[v + 1];
  int j = b0;
  for (; j + 4 <= b1; j += 4) {
    int s0 = csr[j], s1 = csr[j + 1], s2 = csr[j + 2], s3 = csr[j + 3];
    uint4 p0 = t8[(size_t)s0 * 12 + c8];
    uint4 p1 = t8[(size_t)s1 * 12 + c8];
    uint4 p2 = t8[(size_t)s2 * 12 + c8];
    uint4 p3 = t8[(size_t)s3 * 12 + c8];
    float a0[8], a1[8], a2[8], a3[8];
    unpack8(p0, a0); unpack8(p1, a1); unpack8(p2, a2); unpack8(p3, a3);
#pragma unroll
    for (int q = 0; q < 8; q++) acc[q] += (a0[q] + a1[q]) + (a2[q] + a3[q]);
  }
  for (; j < b1; j++) {
    int s = csr[j];
    float a0[8];
    unpack8(t8[(size_t)s * 12 + c8], a0);
#pragma unroll
    for (int q = 0; q < 8; q++) acc[q] += a0[q];
  }
  float dv = dinv[v];
  float4 bA = ((const float4*)bias)[c8 * 2];
  float4 bB = ((const float4*)bias)[c8 * 2 + 1];
  float z[8] = {dv * acc[0] + bA.x, dv * acc[1] + bA.y, dv * acc[2] + bA.z, dv * acc[3] + bA.w,
                dv * acc[4] + bB.x, dv * acc[5] + bB.y, dv * acc[6] + bB.z, dv * acc[7] + bB.w};
  float4 oA, oB;
  if (MODE == 1) {
    oA = make_float4(z[0], z[1], z[2], z[3]);
    oB = make_float4(z[4], z[5], z[6], z[7]);
  } else if (MODE == 2) {
    oA = make_float4(1.0f / (1.0f + expf(-z[0])), 1.0f / (1.0f + expf(-z[1])),
                     1.0f / (1.0f + expf(-z[2])), 1.0f / (1.0f + expf(-z[3])));
    oB = make_float4(1.0f / (1.0f + expf(-z[4])), 1.0f / (1.0f + expf(-z[5])),
                     1.0f / (1.0f + expf(-z[6])), 1.0f / (1.0f + expf(-z[7])));
  } else {
    float4 uA = ((const float4*)g)[idx * 2], uB = ((const float4*)g)[idx * 2 + 1];
    float4 hA = ((const float4*)hprev)[idx * 2], hB = ((const float4*)hprev)[idx * 2 + 1];
    oA = make_float4(uA.x * hA.x + (1.0f - uA.x) * tanhf(z[0]),
                     uA.y * hA.y + (1.0f - uA.y) * tanhf(z[1]),
                     uA.z * hA.z + (1.0f - uA.z) * tanhf(z[2]),
                     uA.w * hA.w + (1.0f - uA.w) * tanhf(z[3]));
    oB = make_float4(uB.x * hB.x + (1.0f - uB.x) * tanhf(z[4]),
                     uB.y * hB.y + (1.0f - uB.y) * tanhf(z[5]),
                     uB.z * hB.z + (1.0f - uB.z) * tanhf(z[6]),
                     uB.w * hB.w + (1.0f - uB.w) * tanhf(z[7]));
  }
  ((float4*)outf)[idx * 2] = oA;
  ((float4*)outf)[idx * 2 + 1] = oB;
}

// ---- launch ----
extern "C" void kernel_launch(void* const* d_in, const int* in_sizes, int n_in,
                              void* d_out, int out_size, void* d_ws, size_t ws_size,
                              hipStream_t stream) {
  const float* x = (const float*)d_in[0];
  const int* ei32 = (const int*)d_in[1];
  const i64* ei64 = (const i64*)d_in[1];
  const unsigned* eiw = (const unsigned*)d_in[1];
  const float* hp = (const float*)d_in[2];
  const float* Wx = (const float*)d_in[3];
  const float* bx = (const float*)d_in[4];
  const float* Wuh = (const float*)d_in[5];
  const float* buh = (const float*)d_in[6];
  const float* Wch = (const float*)d_in[7];
  const float* bch = (const float*)d_in[8];
  float* out = (float*)d_out;

  const int N = in_sizes[0] / D;
  const int E = in_sizes[1] / 2;
  const size_t NF = (size_t)N * D;
  const size_t nPad = ((size_t)N + 1023) & ~(size_t)1023;
  const size_t ePad = ((size_t)E + 63) & ~(size_t)63;

  char* base = (char*)d_ws;
  int* flag = (int*)base;                        // 256 B
  float* dinv = (float*)(base + 256);            // nPad f32
  int* off = (int*)((char*)dinv + nPad * 4);     // nPad + 64 ints
  int* cur = off + nPad + 64;                    // nPad ints
  int* bsum = cur + nPad;                        // 1024 ints
  int* csr = bsum + 1024;                        // ePad ints
  __hip_bfloat16* t = (__hip_bfloat16*)(csr + ePad);  // NF bf16 (16B aligned)
  float* xg = (float*)((char*)t + NF * 2);       // NF f32
  float* g = xg + NF;                            // NF f32

  const int nbN = (N + 255) / 256;
  const int NB = (N + 1023) / 1024;
  const int gb = (N + 63) / 64;                  // 64-row tiles (R10 density)
  const int fb8 = (N * 12 + 255) / 256;
  const int pb = 8 * 256;

  // CSR build + normalization
  k_zero_detect<<<nbN, 256, 0, stream>>>(cur, N, eiw, flag, E);
  k_hist<<<pb, 256, 0, stream>>>(ei32, ei64, flag, cur, E, N);
  k_scan1<<<NB, 1024, 0, stream>>>(cur, off, dinv, bsum, N);
  k_scan2<<<1, 1024, 0, stream>>>(bsum, off, NB, N);
  k_scan3<<<NB, 1024, 0, stream>>>(off, cur, bsum, N);
  k_fill<<<pb, 256, 0, stream>>>(ei32, ei64, flag, cur, csr, E, N);

  // GCN 1: xg = x_gcn
  gemm_kernel<96, 0><<<gb, 256, 0, stream>>>(x, nullptr, nullptr, nullptr, Wx, dinv, t, N);
  gather_fin<1><<<fb8, 256, 0, stream>>>(t, dinv, off, csr, bx, nullptr, nullptr, xg, N);

  // GCN 2: g = sigmoid(GCN([xg, hp]))
  gemm_kernel<192, 1><<<gb, 256, 0, stream>>>(nullptr, xg, hp, nullptr, Wuh, dinv, t, N);
  gather_fin<2><<<fb8, 256, 0, stream>>>(t, dinv, off, csr, buh, nullptr, nullptr, g, N);

  // GCN 3: out = g*hp + (1-g)*tanh(GCN([xg, g*hp]))
  gemm_kernel<192, 2><<<gb, 256, 0, stream>>>(nullptr, xg, hp, g, Wch, dinv, t, N);
  gather_fin<3><<<fb8, 256, 0, stream>>>(t, dinv, off, csr, bch, g, hp, out, N);
}

// Round 14
// 352.712 us; speedup vs baseline: 1.3278x; 1.3278x over previous
//
#include <hip/hip_runtime.h>
#include <hip/hip_bf16.h>

#define D 96
typedef long long i64;

__device__ __forceinline__ float bf2f(unsigned short u) {
  union { unsigned u; float f; } x; x.u = ((unsigned)u) << 16; return x.f;
}
__device__ __forceinline__ void unpack8(uint4 p, float* a) {
  a[0] = bf2f((unsigned short)(p.x & 0xffff)); a[1] = bf2f((unsigned short)(p.x >> 16));
  a[2] = bf2f((unsigned short)(p.y & 0xffff)); a[3] = bf2f((unsigned short)(p.y >> 16));
  a[4] = bf2f((unsigned short)(p.z & 0xffff)); a[5] = bf2f((unsigned short)(p.z >> 16));
  a[6] = bf2f((unsigned short)(p.w & 0xffff)); a[7] = bf2f((unsigned short)(p.w >> 16));
}

// ---- fused: zero cnt + index-width detection (block 0) ----
__global__ __launch_bounds__(256) void k_zero_detect(int* cur, int N,
                                                     const unsigned* __restrict__ w,
                                                     int* flag, int E) {
  int i = blockIdx.x * 256 + threadIdx.x;
  if (i < N) cur[i] = 0;
  if (blockIdx.x == 0 && threadIdx.x < 64) {
    int lane = threadIdx.x;
    int lim = (E < 2048) ? E : 2048;
    unsigned acc = 0;
    for (int j = lane; j < lim; j += 64) acc |= w[2 * j + 1];
#pragma unroll
    for (int off = 32; off > 0; off >>= 1) acc |= __shfl_down(acc, off, 64);
    if (lane == 0) *flag = (acc == 0) ? 1 : 0;  // 1 => int64 storage
  }
}

// ---- histogram of dst, range-partitioned (no cross-XCD line sharing) ----
__global__ __launch_bounds__(256) void k_hist(const int* __restrict__ e32,
                                              const i64* __restrict__ e64,
                                              const int* __restrict__ flagp,
                                              int* cnt, int E, int N) {
  int range = blockIdx.x & 7;
  int sub = blockIdx.x >> 3;
  int B = gridDim.x >> 3;
  int chunk = (E + B - 1) / B;
  int lo = sub * chunk;
  int hi = min(E, lo + chunk);
  int f = *flagp;
  int rlo = (int)(((i64)N * range) >> 3);
  int rhi = (int)(((i64)N * (range + 1)) >> 3);
  for (int i = lo + threadIdx.x; i < hi; i += 256) {
    int d = f ? (int)e64[(size_t)E + i] : e32[(size_t)E + i];
    if (d < rlo || d >= rhi) continue;
    atomicAdd(&cnt[d], 1);
  }
}

// ---- scan phase 1: per-block exclusive scan; fused dinv = rsqrt(cnt+1) ----
__global__ __launch_bounds__(1024) void k_scan1(const int* __restrict__ cnt,
                                                int* __restrict__ off,
                                                float* __restrict__ dinv,
                                                int* __restrict__ bsum, int N) {
  __shared__ int tmp[1024];
  int tid = threadIdx.x;
  int i = blockIdx.x * 1024 + tid;
  int v = (i < N) ? cnt[i] : 0;
  if (i < N) dinv[i] = rsqrtf((float)v + 1.0f);
  tmp[tid] = v;
  __syncthreads();
  for (int s = 1; s < 1024; s <<= 1) {
    int add = (tid >= s) ? tmp[tid - s] : 0;
    __syncthreads();
    tmp[tid] += add;
    __syncthreads();
  }
  if (i < N) off[i] = tmp[tid] - v;
  if (tid == 1023) bsum[blockIdx.x] = tmp[1023];
}

// ---- scan phase 2 ----
__global__ __launch_bounds__(1024) void k_scan2(int* __restrict__ bsum, int* __restrict__ off,
                                                int NB, int N) {
  __shared__ int tmp[1024];
  int tid = threadIdx.x;
  int v = (tid < NB) ? bsum[tid] : 0;
  tmp[tid] = v;
  __syncthreads();
  for (int s = 1; s < 1024; s <<= 1) {
    int add = (tid >= s) ? tmp[tid - s] : 0;
    __syncthreads();
    tmp[tid] += add;
    __syncthreads();
  }
  if (tid < NB) bsum[tid] = tmp[tid] - v;
  if (tid == NB - 1) off[N] = tmp[tid];
}

// ---- scan phase 3 ----
__global__ __launch_bounds__(1024) void k_scan3(int* __restrict__ off, int* __restrict__ cur,
                                                const int* __restrict__ bsum, int N) {
  int i = blockIdx.x * 1024 + threadIdx.x;
  if (i >= N) return;
  int o = off[i] + bsum[blockIdx.x];
  off[i] = o;
  cur[i] = o;
}

// ---- fill CSR, range-partitioned ----
__global__ __launch_bounds__(256) void k_fill(const int* __restrict__ e32,
                                              const i64* __restrict__ e64,
                                              const int* __restrict__ flagp,
                                              int* cur, int* __restrict__ csr, int E, int N) {
  int range = blockIdx.x & 7;
  int sub = blockIdx.x >> 3;
  int B = gridDim.x >> 3;
  int chunk = (E + B - 1) / B;
  int lo = sub * chunk;
  int hi = min(E, lo + chunk);
  int f = *flagp;
  int rlo = (int)(((i64)N * range) >> 3);
  int rhi = (int)(((i64)N * (range + 1)) >> 3);
  for (int i = lo + threadIdx.x; i < hi; i += 256) {
    int d = f ? (int)e64[(size_t)E + i] : e32[(size_t)E + i];
    if (d < rlo || d >= rhi) continue;
    int s = f ? (int)e64[i] : e32[i];
    if ((unsigned)s >= (unsigned)N) continue;
    int pos = atomicAdd(&cur[d], 1);
    csr[pos] = s;
  }
}

// ---- GEMM: t[i,:] = bf16( dinv[i] * (A[i,:] @ W) ) -- R10 structure verbatim ----
// (known good: 42us, VGPR 52. R11/R13 prefetch variants spill; R12 small tile LDS-bound.)
template <int KTOT, int MODE>
__global__ __launch_bounds__(256) void gemm_kernel(
    const float* __restrict__ xin, const float* __restrict__ xg,
    const float* __restrict__ hprev, const float* __restrict__ gmul,
    const float* __restrict__ W, const float* __restrict__ dinv,
    __hip_bfloat16* __restrict__ t, int N) {
  __shared__ float As[32][68];   // [k][row]; 272B stride (16B aligned)
  __shared__ float Ws[32][96];
  const int tid = threadIdx.x;
  const int tx = tid & 15;
  const int ty = tid >> 4;
  const int row0 = blockIdx.x * 64;
  float acc[4][6] = {};

  const int srow = tid >> 3;
  const int skf = tid & 7;

  for (int kc = 0; kc < KTOT; kc += 32) {
#pragma unroll
    for (int i = 0; i < 2; i++) {
      int row = srow + i * 32;
      int grow = row0 + row;
      int gk = kc + 4 * skf;
      float4 v = make_float4(0.f, 0.f, 0.f, 0.f);
      if (grow < N) {
        if (MODE == 0) {
          v = *(const float4*)&xin[(size_t)grow * D + gk];
        } else if (gk < 96) {
          v = *(const float4*)&xg[(size_t)grow * D + gk];
        } else {
          v = *(const float4*)&hprev[(size_t)grow * D + (gk - 96)];
          if (MODE == 2) {
            float4 gm = *(const float4*)&gmul[(size_t)grow * D + (gk - 96)];
            v.x *= gm.x; v.y *= gm.y; v.z *= gm.z; v.w *= gm.w;
          }
        }
      }
      int k0 = 4 * skf;
      As[k0 + 0][row] = v.x;
      As[k0 + 1][row] = v.y;
      As[k0 + 2][row] = v.z;
      As[k0 + 3][row] = v.w;
    }
#pragma unroll
    for (int i = 0; i < 3; i++) {
      int e = tid + i * 256;
      int k = e / 24, c4 = e - k * 24;
      *(float4*)&Ws[k][4 * c4] = *(const float4*)&W[(size_t)(kc + k) * D + 4 * c4];
    }
    __syncthreads();
#pragma unroll
    for (int k = 0; k < 32; k++) {
      float4 a4 = *(const float4*)&As[k][ty * 4];
      float2 b01 = *(const float2*)&Ws[k][tx * 6];
      float2 b23 = *(const float2*)&Ws[k][tx * 6 + 2];
      float2 b45 = *(const float2*)&Ws[k][tx * 6 + 4];
      float a[4] = {a4.x, a4.y, a4.z, a4.w};
      float b[6] = {b01.x, b01.y, b23.x, b23.y, b45.x, b45.y};
#pragma unroll
      for (int r = 0; r < 4; r++)
#pragma unroll
        for (int c = 0; c < 6; c++) acc[r][c] += a[r] * b[c];
    }
    __syncthreads();
  }
#pragma unroll
  for (int r = 0; r < 4; r++) {
    int grow = row0 + ty * 4 + r;
    if (grow >= N) continue;
    float dv = dinv[grow];
#pragma unroll
    for (int c = 0; c < 6; c++) {
      int gc = tx * 6 + c;
      t[(size_t)grow * D + gc] = __float2bfloat16(acc[r][c] * dv);
    }
  }
}

// ---- fused gather-reduce + finalize: bf16 t, 8-elem chunks (12 threads/node) ----
// 8x-unrolled neighbor loop: 8 independent row-loads in flight (deg avg = 16).
template <int MODE>
__global__ __launch_bounds__(256) void gather_fin(
    const __hip_bfloat16* __restrict__ t, const float* __restrict__ dinv,
    const int* __restrict__ off, const int* __restrict__ csr,
    const float* __restrict__ bias,
    const float* __restrict__ g, const float* __restrict__ hprev,
    float* __restrict__ outf, int N) {
  int idx = blockIdx.x * 256 + threadIdx.x;
  int total = N * 12;
  if (idx >= total) return;
  int v = idx / 12;
  int c8 = idx - v * 12;
  const uint4* t8 = (const uint4*)t;
  float acc[8];
  unpack8(t8[(size_t)v * 12 + c8], acc);
  int b0 = off[v], b1 = off[v + 1];
  int j = b0;
  for (; j + 8 <= b1; j += 8) {
    int s0 = csr[j],     s1 = csr[j + 1], s2 = csr[j + 2], s3 = csr[j + 3];
    int s4 = csr[j + 4], s5 = csr[j + 5], s6 = csr[j + 6], s7 = csr[j + 7];
    uint4 p0 = t8[(size_t)s0 * 12 + c8];
    uint4 p1 = t8[(size_t)s1 * 12 + c8];
    uint4 p2 = t8[(size_t)s2 * 12 + c8];
    uint4 p3 = t8[(size_t)s3 * 12 + c8];
    uint4 p4 = t8[(size_t)s4 * 12 + c8];
    uint4 p5 = t8[(size_t)s5 * 12 + c8];
    uint4 p6 = t8[(size_t)s6 * 12 + c8];
    uint4 p7 = t8[(size_t)s7 * 12 + c8];
    float a0[8], a1[8], a2[8], a3[8], a4[8], a5[8], a6[8], a7[8];
    unpack8(p0, a0); unpack8(p1, a1); unpack8(p2, a2); unpack8(p3, a3);
    unpack8(p4, a4); unpack8(p5, a5); unpack8(p6, a6); unpack8(p7, a7);
#pragma unroll
    for (int q = 0; q < 8; q++)
      acc[q] += ((a0[q] + a1[q]) + (a2[q] + a3[q])) + ((a4[q] + a5[q]) + (a6[q] + a7[q]));
  }
  for (; j + 4 <= b1; j += 4) {
    int s0 = csr[j], s1 = csr[j + 1], s2 = csr[j + 2], s3 = csr[j + 3];
    uint4 p0 = t8[(size_t)s0 * 12 + c8];
    uint4 p1 = t8[(size_t)s1 * 12 + c8];
    uint4 p2 = t8[(size_t)s2 * 12 + c8];
    uint4 p3 = t8[(size_t)s3 * 12 + c8];
    float a0[8], a1[8], a2[8], a3[8];
    unpack8(p0, a0); unpack8(p1, a1); unpack8(p2, a2); unpack8(p3, a3);
#pragma unroll
    for (int q = 0; q < 8; q++) acc[q] += (a0[q] + a1[q]) + (a2[q] + a3[q]);
  }
  for (; j < b1; j++) {
    int s = csr[j];
    float a0[8];
    unpack8(t8[(size_t)s * 12 + c8], a0);
#pragma unroll
    for (int q = 0; q < 8; q++) acc[q] += a0[q];
  }
  float dv = dinv[v];
  float4 bA = ((const float4*)bias)[c8 * 2];
  float4 bB = ((const float4*)bias)[c8 * 2 + 1];
  float z[8] = {dv * acc[0] + bA.x, dv * acc[1] + bA.y, dv * acc[2] + bA.z, dv * acc[3] + bA.w,
                dv * acc[4] + bB.x, dv * acc[5] + bB.y, dv * acc[6] + bB.z, dv * acc[7] + bB.w};
  float4 oA, oB;
  if (MODE == 1) {
    oA = make_float4(z[0], z[1], z[2], z[3]);
    oB = make_float4(z[4], z[5], z[6], z[7]);
  } else if (MODE == 2) {
    oA = make_float4(1.0f / (1.0f + expf(-z[0])), 1.0f / (1.0f + expf(-z[1])),
                     1.0f / (1.0f + expf(-z[2])), 1.0f / (1.0f + expf(-z[3])));
    oB = make_float4(1.0f / (1.0f + expf(-z[4])), 1.0f / (1.0f + expf(-z[5])),
                     1.0f / (1.0f + expf(-z[6])), 1.0f / (1.0f + expf(-z[7])));
  } else {
    float4 uA = ((const float4*)g)[idx * 2], uB = ((const float4*)g)[idx * 2 + 1];
    float4 hA = ((const float4*)hprev)[idx * 2], hB = ((const float4*)hprev)[idx * 2 + 1];
    oA = make_float4(uA.x * hA.x + (1.0f - uA.x) * tanhf(z[0]),
                     uA.y * hA.y + (1.0f - uA.y) * tanhf(z[1]),
                     uA.z * hA.z + (1.0f - uA.z) * tanhf(z[2]),
                     uA.w * hA.w + (1.0f - uA.w) * tanhf(z[3]));
    oB = make_float4(uB.x * hB.x + (1.0f - uB.x) * tanhf(z[4]),
                     uB.y * hB.y + (1.0f - uB.y) * tanhf(z[5]),
                     uB.z * hB.z + (1.0f - uB.z) * tanhf(z[6]),
                     uB.w * hB.w + (1.0f - uB.w) * tanhf(z[7]));
  }
  ((float4*)outf)[idx * 2] = oA;
  ((float4*)outf)[idx * 2 + 1] = oB;
}

// ---- launch ----
extern "C" void kernel_launch(void* const* d_in, const int* in_sizes, int n_in,
                              void* d_out, int out_size, void* d_ws, size_t ws_size,
                              hipStream_t stream) {
  const float* x = (const float*)d_in[0];
  const int* ei32 = (const int*)d_in[1];
  const i64* ei64 = (const i64*)d_in[1];
  const unsigned* eiw = (const unsigned*)d_in[1];
  const float* hp = (const float*)d_in[2];
  const float* Wx = (const float*)d_in[3];
  const float* bx = (const float*)d_in[4];
  const float* Wuh = (const float*)d_in[5];
  const float* buh = (const float*)d_in[6];
  const float* Wch = (const float*)d_in[7];
  const float* bch = (const float*)d_in[8];
  float* out = (float*)d_out;

  const int N = in_sizes[0] / D;
  const int E = in_sizes[1] / 2;
  const size_t NF = (size_t)N * D;
  const size_t nPad = ((size_t)N + 1023) & ~(size_t)1023;
  const size_t ePad = ((size_t)E + 63) & ~(size_t)63;

  char* base = (char*)d_ws;
  int* flag = (int*)base;                        // 256 B
  float* dinv = (float*)(base + 256);            // nPad f32
  int* off = (int*)((char*)dinv + nPad * 4);     // nPad + 64 ints
  int* cur = off + nPad + 64;                    // nPad ints
  int* bsum = cur + nPad;                        // 1024 ints
  int* csr = bsum + 1024;                        // ePad ints
  __hip_bfloat16* t = (__hip_bfloat16*)(csr + ePad);  // NF bf16 (16B aligned)
  float* xg = (float*)((char*)t + NF * 2);       // NF f32
  float* g = xg + NF;                            // NF f32

  const int nbN = (N + 255) / 256;
  const int NB = (N + 1023) / 1024;
  const int gb = (N + 63) / 64;
  const int fb8 = (N * 12 + 255) / 256;
  const int pb = 8 * 256;

  // CSR build + normalization
  k_zero_detect<<<nbN, 256, 0, stream>>>(cur, N, eiw, flag, E);
  k_hist<<<pb, 256, 0, stream>>>(ei32, ei64, flag, cur, E, N);
  k_scan1<<<NB, 1024, 0, stream>>>(cur, off, dinv, bsum, N);
  k_scan2<<<1, 1024, 0, stream>>>(bsum, off, NB, N);
  k_scan3<<<NB, 1024, 0, stream>>>(off, cur, bsum, N);
  k_fill<<<pb, 256, 0, stream>>>(ei32, ei64, flag, cur, csr, E, N);

  // GCN 1: xg = x_gcn
  gemm_kernel<96, 0><<<gb, 256, 0, stream>>>(x, nullptr, nullptr, nullptr, Wx, dinv, t, N);
  gather_fin<1><<<fb8, 256, 0, stream>>>(t, dinv, off, csr, bx, nullptr, nullptr, xg, N);

  // GCN 2: g = sigmoid(GCN([xg, hp]))
  gemm_kernel<192, 1><<<gb, 256, 0, stream>>>(nullptr, xg, hp, nullptr, Wuh, dinv, t, N);
  gather_fin<2><<<fb8, 256, 0, stream>>>(t, dinv, off, csr, buh, nullptr, nullptr, g, N);

  // GCN 3: out = g*hp + (1-g)*tanh(GCN([xg, g*hp]))
  gemm_kernel<192, 2><<<gb, 256, 0, stream>>>(nullptr, xg, hp, g, Wch, dinv, t, N);
  gather_fin<3><<<fb8, 256, 0, stream>>>(t, dinv, off, csr, bch, g, hp, out, N);
}